// Round 14
// baseline (648.748 us; speedup 1.0000x reference)
//
#include <hip/hip_runtime.h>
#include <hip/hip_bf16.h>

#define LN_EPS 1e-5f

typedef __attribute__((ext_vector_type(8))) short bf16x8;
typedef __attribute__((ext_vector_type(4))) float f32x4;

__device__ __forceinline__ short f2bf(float x) {
    union { float f; unsigned u; } v; v.f = x;
    unsigned r = v.u + 0x7fff + ((v.u >> 16) & 1);   // RNE to bf16
    return (short)(r >> 16);
}

#define IN_STRIDE 528   // 512 data bytes + 16 pad
#define H_STRIDE  272   // 256 data bytes + 16 pad

// R12 structure (single 35 KB LDS buffer -> 4 blocks/CU) + zero-LDS-cost
// pipeline: next tile's global loads issue right after the last inA read and
// fly across L2/LN/store as raw float4 regs; cvt+ds_write at next loop top.
// 3 barriers/tile (loop-top barrier proven redundant).
__global__ __launch_bounds__(256, 3) void mpnn_mfma(
    const float* __restrict__ inR, const float* __restrict__ inL,
    const float* __restrict__ W1, const float* __restrict__ b1,
    const float* __restrict__ W2, const float* __restrict__ b2,
    const float* __restrict__ gamma, const float* __restrict__ beta,
    float* __restrict__ out, int E, int niters)
{
    __shared__ __align__(16) char inA[32 * IN_STRIDE];  // input tile (bf16)
    __shared__ __align__(16) char hbuf[64 * H_STRIDE];  // h1 exchange (bf16)
    __shared__ float2 lnp[4][4][16];                    // [wave][v][r] = (sum, sumsq)

    const int tid  = threadIdx.x;
    const int lane = tid & 63;
    const int wave = tid >> 6;
    const int r    = lane & 15;
    const int q    = lane >> 4;

    // ---- weight fragments from fp32 globals (once per block, L2-resident) ----
    bf16x8 A1[2][8], A2[2][4];
    float4 b1v[2], b2v[2], gv[2], bv[2];
#pragma unroll
    for (int t = 0; t < 2; ++t) {
        const int fr = wave * 32 + t * 16 + r;
#pragma unroll
        for (int c = 0; c < 8; ++c)
#pragma unroll
            for (int i = 0; i < 8; ++i)
                A1[t][c][i] = f2bf(W1[(c * 32 + q * 8 + i) * 128 + fr]);
#pragma unroll
        for (int c = 0; c < 4; ++c)
#pragma unroll
            for (int i = 0; i < 8; ++i)
                A2[t][c][i] = f2bf(W2[(c * 32 + q * 8 + i) * 128 + fr]);
        const int fq = wave * 32 + t * 16 + q * 4;
        b1v[t] = *(const float4*)(b1 + fq);
        b2v[t] = *(const float4*)(b2 + fq);
        gv[t]  = *(const float4*)(gamma + fq);
        bv[t]  = *(const float4*)(beta + fq);
    }

    float4 raw[8];   // in-flight raw fp32 of the NEXT tile (32 VGPR)
    auto issue = [&](int itx) {
#pragma unroll
        for (int j = 0; j < 4; ++j) {
            const int idx = j * 256 + tid;   // [0,1024) = [e 0..31][hw][c8 0..15]
            const int e  = idx >> 5;
            const int hw = (idx >> 4) & 1;   // 0: left half (k<128), 1: right half
            const int c8 = idx & 15;
            long ee = (long)itx * 32 + e; if (ee >= E) ee = E - 1;
            const float* src = hw ? inR : inL;
            raw[2 * j]     = *(const float4*)(src + ee * 128 + c8 * 8);
            raw[2 * j + 1] = *(const float4*)(src + ee * 128 + c8 * 8 + 4);
        }
    };
    auto cvtwrite = [&]() {
#pragma unroll
        for (int j = 0; j < 4; ++j) {
            const int idx = j * 256 + tid;
            const int e  = idx >> 5;
            const int hw = (idx >> 4) & 1;
            const int c8 = idx & 15;
            const float4 v0 = raw[2 * j], v1 = raw[2 * j + 1];
            bf16x8 s;
            s[0] = f2bf(v0.x); s[1] = f2bf(v0.y); s[2] = f2bf(v0.z); s[3] = f2bf(v0.w);
            s[4] = f2bf(v1.x); s[5] = f2bf(v1.y); s[6] = f2bf(v1.z); s[7] = f2bf(v1.w);
            *(bf16x8*)(&inA[e * IN_STRIDE + hw * 256 + c8 * 16]) = s;
        }
    };

    int it = blockIdx.x;
    if (it < niters) issue(it);

    for (; it < niters; it += gridDim.x) {
        const int e0  = it * 32;
        const int itn = it + gridDim.x;

        cvtwrite();          // raw (this tile) -> inA
        __syncthreads();     // (1) inA ready

        // ---- layer 1: D[f][e]; lr pairs W1 chunk c with data chunk c,
        //      rl pairs W1 chunk (c+4)&7 with data chunk c ----
        f32x4 accL[2][2], accR[2][2];
#pragma unroll
        for (int t = 0; t < 2; ++t)
#pragma unroll
            for (int u = 0; u < 2; ++u) {
                accL[t][u] = f32x4{0.f, 0.f, 0.f, 0.f};
                accR[t][u] = f32x4{0.f, 0.f, 0.f, 0.f};
            }
#pragma unroll
        for (int c = 0; c < 8; ++c) {
            const bf16x8 x0 = *(const bf16x8*)(&inA[r        * IN_STRIDE + c * 64 + q * 16]);
            const bf16x8 x1 = *(const bf16x8*)(&inA[(16 + r) * IN_STRIDE + c * 64 + q * 16]);
            const int crl = (c + 4) & 7;
#pragma unroll
            for (int t = 0; t < 2; ++t) {
                accL[t][0] = __builtin_amdgcn_mfma_f32_16x16x32_bf16(A1[t][c],   x0, accL[t][0], 0, 0, 0);
                accL[t][1] = __builtin_amdgcn_mfma_f32_16x16x32_bf16(A1[t][c],   x1, accL[t][1], 0, 0, 0);
                accR[t][0] = __builtin_amdgcn_mfma_f32_16x16x32_bf16(A1[t][crl], x0, accR[t][0], 0, 0, 0);
                accR[t][1] = __builtin_amdgcn_mfma_f32_16x16x32_bf16(A1[t][crl], x1, accR[t][1], 0, 0, 0);
            }
        }

        // ---- issue next tile's loads: in flight across L2/LN/store ----
        if (itn < niters) issue(itn);

        // ---- h1 = relu(. + b1) -> hbuf ----
#pragma unroll
        for (int t = 0; t < 2; ++t) {
            const int fb = wave * 32 + t * 16 + q * 4;
#pragma unroll
            for (int v = 0; v < 4; ++v) {
                const f32x4 a = (v < 2) ? accL[t][v] : accR[t][v - 2];
                short4 s;
                s.x = f2bf(fmaxf(a[0] + b1v[t].x, 0.f));
                s.y = f2bf(fmaxf(a[1] + b1v[t].y, 0.f));
                s.z = f2bf(fmaxf(a[2] + b1v[t].z, 0.f));
                s.w = f2bf(fmaxf(a[3] + b1v[t].w, 0.f));
                *(short4*)(&hbuf[(v * 16 + r) * H_STRIDE + fb * 2]) = s;
            }
        }
        __syncthreads();   // (2) hbuf ready; all inA reads complete

        // ---- layer 2 ----
        f32x4 acc2[2][4];
#pragma unroll
        for (int t = 0; t < 2; ++t)
#pragma unroll
            for (int v = 0; v < 4; ++v) acc2[t][v] = f32x4{0.f, 0.f, 0.f, 0.f};
#pragma unroll
        for (int c = 0; c < 4; ++c) {
#pragma unroll
            for (int v = 0; v < 4; ++v) {
                const bf16x8 y = *(const bf16x8*)(&hbuf[(v * 16 + r) * H_STRIDE + c * 64 + q * 16]);
#pragma unroll
                for (int t = 0; t < 2; ++t)
                    acc2[t][v] = __builtin_amdgcn_mfma_f32_16x16x32_bf16(A2[t][c], y, acc2[t][v], 0, 0, 0);
            }
        }

        // ---- bias + relu + LN partials ----
        float s1[4] = {0.f, 0.f, 0.f, 0.f}, s2[4] = {0.f, 0.f, 0.f, 0.f};
#pragma unroll
        for (int t = 0; t < 2; ++t)
#pragma unroll
            for (int v = 0; v < 4; ++v) {
                f32x4 a = acc2[t][v];
                a[0] = fmaxf(a[0] + b2v[t].x, 0.f);
                a[1] = fmaxf(a[1] + b2v[t].y, 0.f);
                a[2] = fmaxf(a[2] + b2v[t].z, 0.f);
                a[3] = fmaxf(a[3] + b2v[t].w, 0.f);
                acc2[t][v] = a;
                s1[v] += a[0] + a[1] + a[2] + a[3];
                s2[v] += a[0] * a[0] + a[1] * a[1] + a[2] * a[2] + a[3] * a[3];
            }
#pragma unroll
        for (int v = 0; v < 4; ++v) {
            s1[v] += __shfl_xor(s1[v], 16);
            s1[v] += __shfl_xor(s1[v], 32);
            s2[v] += __shfl_xor(s2[v], 16);
            s2[v] += __shfl_xor(s2[v], 32);
        }
        if (lane < 16) {
#pragma unroll
            for (int v = 0; v < 4; ++v)
                lnp[wave][v][lane] = make_float2(s1[v], s2[v]);
        }
        __syncthreads();   // (3) partials ready

        // ---- finalize LN + fp32 stores ----
#pragma unroll
        for (int v = 0; v < 4; ++v) {
            float S1 = 0.f, S2 = 0.f;
#pragma unroll
            for (int w = 0; w < 4; ++w) {
                const float2 p = lnp[w][v][r];
                S1 += p.x; S2 += p.y;
            }
            const float mu  = S1 * (1.f / 128.f);
            const float var = S2 * (1.f / 128.f) - mu * mu;
            const float rs  = rsqrtf(var + LN_EPS);
            const int el = (v & 1) * 16 + r;
            const bool ok = (e0 + el) < E;
            const long orow = ((v < 2) ? 0L : (long)E) + e0 + el;
#pragma unroll
            for (int t = 0; t < 2; ++t) {
                const int fb = wave * 32 + t * 16 + q * 4;
                const f32x4 a = acc2[t][v];
                float4 o;
                o.x = (a[0] - mu) * rs * gv[t].x + bv[t].x;
                o.y = (a[1] - mu) * rs * gv[t].y + bv[t].y;
                o.z = (a[2] - mu) * rs * gv[t].z + bv[t].z;
                o.w = (a[3] - mu) * rs * gv[t].w + bv[t].w;
                if (ok)
                    *(float4*)(out + orow * 128 + fb) = o;
            }
        }
        // NOTE: no loop-top barrier needed — next cvtwrite touches inA only,
        // whose readers (L1) all completed before barrier (2) of this iter.
    }
}

extern "C" void kernel_launch(void* const* d_in, const int* in_sizes, int n_in,
                              void* d_out, int out_size, void* d_ws, size_t ws_size,
                              hipStream_t stream) {
    // Validated interface: dict order, fp32 inputs, fp32 output.
    const float* inR   = (const float*)d_in[0];
    const float* inL   = (const float*)d_in[1];
    const float* W1    = (const float*)d_in[2];
    const float* b1    = (const float*)d_in[3];
    const float* W2    = (const float*)d_in[4];
    const float* b2    = (const float*)d_in[5];
    const float* gamma = (const float*)d_in[6];
    const float* beta  = (const float*)d_in[7];
    const int E = in_sizes[0] / 128;

    const int niters = (E + 31) / 32;
    const int d = (niters + 2047) / 2048;        // tiles per block (balanced)
    const int grid = (niters + d - 1) / d;
    mpnn_mfma<<<grid, 256, 0, stream>>>(inR, inL, W1, b1, W2, b2, gamma, beta,
                                        (float*)d_out, E, niters);
}

// Round 15
// 647.904 us; speedup vs baseline: 1.0013x; 1.0013x over previous
//
#include <hip/hip_runtime.h>
#include <hip/hip_bf16.h>

#define LN_EPS 1e-5f

typedef __attribute__((ext_vector_type(8))) short bf16x8;
typedef __attribute__((ext_vector_type(4))) float f32x4;

__device__ __forceinline__ short f2bf(float x) {
    union { float f; unsigned u; } v; v.f = x;
    unsigned r = v.u + 0x7fff + ((v.u >> 16) & 1);   // RNE to bf16
    return (short)(r >> 16);
}

__device__ __forceinline__ void gload_lds16(const float* g, void* lds) {
    typedef const __attribute__((address_space(1))) unsigned int* gp_t;
    typedef __attribute__((address_space(3))) unsigned int* lp_t;
    __builtin_amdgcn_global_load_lds((gp_t)(const void*)g, (lp_t)lds, 16, 0, 0);
}

#define H_STRIDE 272   // 256 data bytes + 16 pad

// R12 structure + zero-cost async staging: input tile staged RAW FP32 into
// linear LDS via global_load_lds (no VGPR round-trip, no second buffer);
// fp32->bf16 conversion fused into L1 fragment reads. Async issue for tile
// t+1 happens after barrier-2 and flies under L2+LN+stores.
// Block = 256 threads = 4 waves; wave w owns features [32w, 32w+32).
// Each iteration: 32 edges -> 64 output rows (32 lr + 32 rl).
__global__ __launch_bounds__(256, 3) void mpnn_mfma(
    const float* __restrict__ inR, const float* __restrict__ inL,
    const float* __restrict__ W1, const float* __restrict__ b1,
    const float* __restrict__ W2, const float* __restrict__ b2,
    const float* __restrict__ gamma, const float* __restrict__ beta,
    float* __restrict__ out, int E, int niters)
{
    __shared__ __align__(16) float inAf[32 * 256];      // raw fp32 input tile, LINEAR (DMA dest)
    __shared__ __align__(16) char hbuf[64 * H_STRIDE];  // h1 exchange (bf16)
    __shared__ float2 lnp[4][4][16];                    // [wave][v][r] = (sum, sumsq)

    const int tid  = threadIdx.x;
    const int lane = tid & 63;
    const int wave = tid >> 6;
    const int r    = lane & 15;
    const int q    = lane >> 4;

    // ---- weight fragments from fp32 globals (once per block, L2-resident) ----
    bf16x8 A1[2][8], A2[2][4];
    float4 b1v[2], b2v[2], gv[2], bv[2];
#pragma unroll
    for (int t = 0; t < 2; ++t) {
        const int fr = wave * 32 + t * 16 + r;
#pragma unroll
        for (int c = 0; c < 8; ++c)
#pragma unroll
            for (int i = 0; i < 8; ++i)
                A1[t][c][i] = f2bf(W1[(c * 32 + q * 8 + i) * 128 + fr]);
#pragma unroll
        for (int c = 0; c < 4; ++c)
#pragma unroll
            for (int i = 0; i < 8; ++i)
                A2[t][c][i] = f2bf(W2[(c * 32 + q * 8 + i) * 128 + fr]);
        const int fq = wave * 32 + t * 16 + q * 4;
        b1v[t] = *(const float4*)(b1 + fq);
        b2v[t] = *(const float4*)(b2 + fq);
        gv[t]  = *(const float4*)(gamma + fq);
        bv[t]  = *(const float4*)(beta + fq);
    }

    // async staging: wave w stages rows {4*rr + w}; one global_load_lds per row
    // (64 lanes x 16B = 1024B = one full row; lanes 0-31 from inL, 32-63 from inR).
    auto issue = [&](int itx) {
#pragma unroll
        for (int rr = 0; rr < 8; ++rr) {
            const int er = rr * 4 + wave;                 // row (wave-uniform)
            long ee = (long)itx * 32 + er; if (ee >= E) ee = E - 1;
            const float* g = (lane < 32) ? (inL + ee * 128 + lane * 4)
                                         : (inR + ee * 128 + (lane - 32) * 4);
            gload_lds16(g, (void*)(inAf + er * 256));
        }
    };

    int it = blockIdx.x;
    if (it < niters) issue(it);

    for (; it < niters; it += gridDim.x) {
        const int e0  = it * 32;
        const int itn = it + gridDim.x;

        asm volatile("s_waitcnt vmcnt(0)" ::: "memory");
        __builtin_amdgcn_sched_barrier(0);
        __syncthreads();   // (1) inAf ready; prev iter's lnp readers done

        // ---- layer 1: fragments read fp32 from LDS, cvt to bf16 in-reg ----
        f32x4 accL[2][2], accR[2][2];
#pragma unroll
        for (int t = 0; t < 2; ++t)
#pragma unroll
            for (int u = 0; u < 2; ++u) {
                accL[t][u] = f32x4{0.f, 0.f, 0.f, 0.f};
                accR[t][u] = f32x4{0.f, 0.f, 0.f, 0.f};
            }
#pragma unroll
        for (int c = 0; c < 8; ++c) {
            const float* p0 = inAf + r * 256        + c * 32 + q * 8;
            const float* p1 = inAf + (16 + r) * 256 + c * 32 + q * 8;
            const float4 f00 = *(const float4*)(p0), f01 = *(const float4*)(p0 + 4);
            const float4 f10 = *(const float4*)(p1), f11 = *(const float4*)(p1 + 4);
            bf16x8 x0, x1;
            x0[0] = f2bf(f00.x); x0[1] = f2bf(f00.y); x0[2] = f2bf(f00.z); x0[3] = f2bf(f00.w);
            x0[4] = f2bf(f01.x); x0[5] = f2bf(f01.y); x0[6] = f2bf(f01.z); x0[7] = f2bf(f01.w);
            x1[0] = f2bf(f10.x); x1[1] = f2bf(f10.y); x1[2] = f2bf(f10.z); x1[3] = f2bf(f10.w);
            x1[4] = f2bf(f11.x); x1[5] = f2bf(f11.y); x1[6] = f2bf(f11.z); x1[7] = f2bf(f11.w);
            const int crl = (c + 4) & 7;
#pragma unroll
            for (int t = 0; t < 2; ++t) {
                accL[t][0] = __builtin_amdgcn_mfma_f32_16x16x32_bf16(A1[t][c],   x0, accL[t][0], 0, 0, 0);
                accL[t][1] = __builtin_amdgcn_mfma_f32_16x16x32_bf16(A1[t][c],   x1, accL[t][1], 0, 0, 0);
                accR[t][0] = __builtin_amdgcn_mfma_f32_16x16x32_bf16(A1[t][crl], x0, accR[t][0], 0, 0, 0);
                accR[t][1] = __builtin_amdgcn_mfma_f32_16x16x32_bf16(A1[t][crl], x1, accR[t][1], 0, 0, 0);
            }
        }

        // ---- h1 = relu(. + b1) -> hbuf ----
#pragma unroll
        for (int t = 0; t < 2; ++t) {
            const int fb = wave * 32 + t * 16 + q * 4;
#pragma unroll
            for (int v = 0; v < 4; ++v) {
                const f32x4 a = (v < 2) ? accL[t][v] : accR[t][v - 2];
                short4 s;
                s.x = f2bf(fmaxf(a[0] + b1v[t].x, 0.f));
                s.y = f2bf(fmaxf(a[1] + b1v[t].y, 0.f));
                s.z = f2bf(fmaxf(a[2] + b1v[t].z, 0.f));
                s.w = f2bf(fmaxf(a[3] + b1v[t].w, 0.f));
                *(short4*)(&hbuf[(v * 16 + r) * H_STRIDE + fb * 2]) = s;
            }
        }
        __syncthreads();   // (2) hbuf ready; ALL inAf reads complete

        // ---- async-issue next tile into inAf (flies under L2 + LN + stores) ----
        if (itn < niters) issue(itn);

        // ---- layer 2 ----
        f32x4 acc2[2][4];
#pragma unroll
        for (int t = 0; t < 2; ++t)
#pragma unroll
            for (int v = 0; v < 4; ++v) acc2[t][v] = f32x4{0.f, 0.f, 0.f, 0.f};
#pragma unroll
        for (int c = 0; c < 4; ++c) {
#pragma unroll
            for (int v = 0; v < 4; ++v) {
                const bf16x8 y = *(const bf16x8*)(&hbuf[(v * 16 + r) * H_STRIDE + c * 64 + q * 16]);
#pragma unroll
                for (int t = 0; t < 2; ++t)
                    acc2[t][v] = __builtin_amdgcn_mfma_f32_16x16x32_bf16(A2[t][c], y, acc2[t][v], 0, 0, 0);
            }
        }

        // ---- bias + relu + LN partials ----
        float s1[4] = {0.f, 0.f, 0.f, 0.f}, s2[4] = {0.f, 0.f, 0.f, 0.f};
#pragma unroll
        for (int t = 0; t < 2; ++t)
#pragma unroll
            for (int v = 0; v < 4; ++v) {
                f32x4 a = acc2[t][v];
                a[0] = fmaxf(a[0] + b2v[t].x, 0.f);
                a[1] = fmaxf(a[1] + b2v[t].y, 0.f);
                a[2] = fmaxf(a[2] + b2v[t].z, 0.f);
                a[3] = fmaxf(a[3] + b2v[t].w, 0.f);
                acc2[t][v] = a;
                s1[v] += a[0] + a[1] + a[2] + a[3];
                s2[v] += a[0] * a[0] + a[1] * a[1] + a[2] * a[2] + a[3] * a[3];
            }
#pragma unroll
        for (int v = 0; v < 4; ++v) {
            s1[v] += __shfl_xor(s1[v], 16);
            s1[v] += __shfl_xor(s1[v], 32);
            s2[v] += __shfl_xor(s2[v], 16);
            s2[v] += __shfl_xor(s2[v], 32);
        }
        if (lane < 16) {
#pragma unroll
            for (int v = 0; v < 4; ++v)
                lnp[wave][v][lane] = make_float2(s1[v], s2[v]);
        }
        __syncthreads();   // (3) partials ready

        // ---- finalize LN + fp32 stores ----
#pragma unroll
        for (int v = 0; v < 4; ++v) {
            float S1 = 0.f, S2 = 0.f;
#pragma unroll
            for (int w = 0; w < 4; ++w) {
                const float2 p = lnp[w][v][r];
                S1 += p.x; S2 += p.y;
            }
            const float mu  = S1 * (1.f / 128.f);
            const float var = S2 * (1.f / 128.f) - mu * mu;
            const float rs  = rsqrtf(var + LN_EPS);
            const int el = (v & 1) * 16 + r;
            const bool ok = (e0 + el) < E;
            const long orow = ((v < 2) ? 0L : (long)E) + e0 + el;
#pragma unroll
            for (int t = 0; t < 2; ++t) {
                const int fb = wave * 32 + t * 16 + q * 4;
                const f32x4 a = acc2[t][v];
                float4 o;
                o.x = (a[0] - mu) * rs * gv[t].x + bv[t].x;
                o.y = (a[1] - mu) * rs * gv[t].y + bv[t].y;
                o.z = (a[2] - mu) * rs * gv[t].z + bv[t].z;
                o.w = (a[3] - mu) * rs * gv[t].w + bv[t].w;
                if (ok)
                    *(float4*)(out + orow * 128 + fb) = o;
            }
        }
    }
}

extern "C" void kernel_launch(void* const* d_in, const int* in_sizes, int n_in,
                              void* d_out, int out_size, void* d_ws, size_t ws_size,
                              hipStream_t stream) {
    // Validated interface: dict order, fp32 inputs, fp32 output.
    const float* inR   = (const float*)d_in[0];
    const float* inL   = (const float*)d_in[1];
    const float* W1    = (const float*)d_in[2];
    const float* b1    = (const float*)d_in[3];
    const float* W2    = (const float*)d_in[4];
    const float* b2    = (const float*)d_in[5];
    const float* gamma = (const float*)d_in[6];
    const float* beta  = (const float*)d_in[7];
    const int E = in_sizes[0] / 128;

    const int niters = (E + 31) / 32;
    const int d = (niters + 2047) / 2048;        // tiles per block (balanced)
    const int grid = (niters + d - 1) / d;
    mpnn_mfma<<<grid, 256, 0, stream>>>(inR, inL, W1, b1, W2, b2, gamma, beta,
                                        (float*)d_out, E, niters);
}

// Round 16
// 235.322 us; speedup vs baseline: 2.7569x; 2.7533x over previous
//
#include <hip/hip_runtime.h>
#include <hip/hip_bf16.h>

#define LN_EPS 1e-5f

typedef __attribute__((ext_vector_type(8))) short bf16x8;
typedef __attribute__((ext_vector_type(4))) float f32x4;

__device__ __forceinline__ short f2bf(float x) {
    union { float f; unsigned u; } v; v.f = x;
    unsigned r = v.u + 0x7fff + ((v.u >> 16) & 1);   // RNE to bf16
    return (short)(r >> 16);
}

#define IN_STRIDE 528   // 512 data bytes + 16 pad
#define H_STRIDE  272   // 256 data bytes + 16 pad

// R12 schedule exactly (best: 224 us), with register-total cuts to cross the
// 170-reg occupancy step (2 -> 3 blocks/CU):
//   - bias/gamma/beta moved from 32 persistent VGPRs to a 2 KB LDS table
//   - L1 and L2 accumulators merged into one reused acc[2][4] (64 -> 32 AGPR)
// No launch-bounds coercion (R14 lesson: forcing waves causes weight spill).
__global__ __launch_bounds__(256) void mpnn_mfma(
    const float* __restrict__ inR, const float* __restrict__ inL,
    const float* __restrict__ W1, const float* __restrict__ b1,
    const float* __restrict__ W2, const float* __restrict__ b2,
    const float* __restrict__ gamma, const float* __restrict__ beta,
    float* __restrict__ out, int E, int niters)
{
    __shared__ __align__(16) char inA[32 * IN_STRIDE];  // input tile (bf16)
    __shared__ __align__(16) char hbuf[64 * H_STRIDE];  // h1 exchange (bf16)
    __shared__ float2 lnp[4][4][16];                    // [wave][v][r] = (sum, sumsq)
    __shared__ __align__(16) float bgl[4][128];         // b1, b2, gamma, beta (fp32)

    const int tid  = threadIdx.x;
    const int lane = tid & 63;
    const int wave = tid >> 6;
    const int r    = lane & 15;
    const int q    = lane >> 4;

    // ---- stage bias/gamma/beta into LDS once ----
    if (tid < 128) {
        bgl[0][tid] = b1[tid];
        bgl[1][tid] = b2[tid];
        bgl[2][tid] = gamma[tid];
        bgl[3][tid] = beta[tid];
    }

    // ---- weight fragments from fp32 globals (once per block, L2-resident) ----
    bf16x8 A1[2][8], A2[2][4];
#pragma unroll
    for (int t = 0; t < 2; ++t) {
        const int fr = wave * 32 + t * 16 + r;
#pragma unroll
        for (int c = 0; c < 8; ++c)
#pragma unroll
            for (int i = 0; i < 8; ++i)
                A1[t][c][i] = f2bf(W1[(c * 32 + q * 8 + i) * 128 + fr]);
#pragma unroll
        for (int c = 0; c < 4; ++c)
#pragma unroll
            for (int i = 0; i < 8; ++i)
                A2[t][c][i] = f2bf(W2[(c * 32 + q * 8 + i) * 128 + fr]);
    }

    for (int it = blockIdx.x; it < niters; it += gridDim.x) {
        const int e0 = it * 32;
        __syncthreads();   // prev iteration's LDS readers done (also covers bgl init)

        // ---- stage 32 edges x 256 k as bf16 (fp32 loads, short8 LDS writes) ----
#pragma unroll
        for (int j = 0; j < 4; ++j) {
            const int idx = j * 256 + tid;       // [0,1024) = [e 0..31][hw][c8 0..15]
            const int e  = idx >> 5;
            const int hw = (idx >> 4) & 1;       // 0: left half (k<128), 1: right half
            const int c8 = idx & 15;             // 8-float group within half-row
            int ee = e0 + e; if (ee >= E) ee = E - 1;
            const float* src = hw ? inR : inL;   // msg = left || right
            const float4 v0 = *(const float4*)(src + (long)ee * 128 + c8 * 8);
            const float4 v1 = *(const float4*)(src + (long)ee * 128 + c8 * 8 + 4);
            bf16x8 s;
            s[0] = f2bf(v0.x); s[1] = f2bf(v0.y); s[2] = f2bf(v0.z); s[3] = f2bf(v0.w);
            s[4] = f2bf(v1.x); s[5] = f2bf(v1.y); s[6] = f2bf(v1.z); s[7] = f2bf(v1.w);
            *(bf16x8*)(&inA[e * IN_STRIDE + hw * 256 + c8 * 16]) = s;
        }
        __syncthreads();   // inA ready

        // ---- layer 1 into acc[t][u]: u=0,1 -> lr e-tiles; u=2,3 -> rl e-tiles ----
        f32x4 acc[2][4];
#pragma unroll
        for (int t = 0; t < 2; ++t)
#pragma unroll
            for (int u = 0; u < 4; ++u)
                acc[t][u] = f32x4{0.f, 0.f, 0.f, 0.f};
#pragma unroll
        for (int c = 0; c < 8; ++c) {
            const bf16x8 x0 = *(const bf16x8*)(&inA[r        * IN_STRIDE + c * 64 + q * 16]);
            const bf16x8 x1 = *(const bf16x8*)(&inA[(16 + r) * IN_STRIDE + c * 64 + q * 16]);
            const int crl = (c + 4) & 7;
#pragma unroll
            for (int t = 0; t < 2; ++t) {
                acc[t][0] = __builtin_amdgcn_mfma_f32_16x16x32_bf16(A1[t][c],   x0, acc[t][0], 0, 0, 0);
                acc[t][1] = __builtin_amdgcn_mfma_f32_16x16x32_bf16(A1[t][c],   x1, acc[t][1], 0, 0, 0);
                acc[t][2] = __builtin_amdgcn_mfma_f32_16x16x32_bf16(A1[t][crl], x0, acc[t][2], 0, 0, 0);
                acc[t][3] = __builtin_amdgcn_mfma_f32_16x16x32_bf16(A1[t][crl], x1, acc[t][3], 0, 0, 0);
            }
        }

        // ---- h1 = relu(. + b1) -> hbuf; erow: [0,32)=lr, [32,64)=rl ----
#pragma unroll
        for (int t = 0; t < 2; ++t) {
            const int fq = wave * 32 + t * 16 + q * 4;
            const float4 b1v = *(const float4*)(&bgl[0][fq]);
#pragma unroll
            for (int v = 0; v < 4; ++v) {
                const f32x4 a = acc[t][v];
                short4 s;
                s.x = f2bf(fmaxf(a[0] + b1v.x, 0.f));
                s.y = f2bf(fmaxf(a[1] + b1v.y, 0.f));
                s.z = f2bf(fmaxf(a[2] + b1v.z, 0.f));
                s.w = f2bf(fmaxf(a[3] + b1v.w, 0.f));
                *(short4*)(&hbuf[(v * 16 + r) * H_STRIDE + fq * 2]) = s;
            }
        }
        __syncthreads();   // hbuf ready; inA reads complete

        // ---- layer 2: reuse acc (L1 values dead) ----
#pragma unroll
        for (int t = 0; t < 2; ++t)
#pragma unroll
            for (int v = 0; v < 4; ++v) acc[t][v] = f32x4{0.f, 0.f, 0.f, 0.f};
#pragma unroll
        for (int c = 0; c < 4; ++c) {
#pragma unroll
            for (int v = 0; v < 4; ++v) {
                const bf16x8 y = *(const bf16x8*)(&hbuf[(v * 16 + r) * H_STRIDE + c * 64 + q * 16]);
#pragma unroll
                for (int t = 0; t < 2; ++t)
                    acc[t][v] = __builtin_amdgcn_mfma_f32_16x16x32_bf16(A2[t][c], y, acc[t][v], 0, 0, 0);
            }
        }

        // ---- bias + relu + LN partials ----
        float s1[4] = {0.f, 0.f, 0.f, 0.f}, s2[4] = {0.f, 0.f, 0.f, 0.f};
#pragma unroll
        for (int t = 0; t < 2; ++t) {
            const int fq = wave * 32 + t * 16 + q * 4;
            const float4 b2v = *(const float4*)(&bgl[1][fq]);
#pragma unroll
            for (int v = 0; v < 4; ++v) {
                f32x4 a = acc[t][v];
                a[0] = fmaxf(a[0] + b2v.x, 0.f);
                a[1] = fmaxf(a[1] + b2v.y, 0.f);
                a[2] = fmaxf(a[2] + b2v.z, 0.f);
                a[3] = fmaxf(a[3] + b2v.w, 0.f);
                acc[t][v] = a;
                s1[v] += a[0] + a[1] + a[2] + a[3];
                s2[v] += a[0] * a[0] + a[1] * a[1] + a[2] * a[2] + a[3] * a[3];
            }
        }
#pragma unroll
        for (int v = 0; v < 4; ++v) {
            s1[v] += __shfl_xor(s1[v], 16);
            s1[v] += __shfl_xor(s1[v], 32);
            s2[v] += __shfl_xor(s2[v], 16);
            s2[v] += __shfl_xor(s2[v], 32);
        }
        if (lane < 16) {
#pragma unroll
            for (int v = 0; v < 4; ++v)
                lnp[wave][v][lane] = make_float2(s1[v], s2[v]);
        }
        __syncthreads();   // partials ready

        // ---- finalize LN + fp32 stores ----
#pragma unroll
        for (int v = 0; v < 4; ++v) {
            float S1 = 0.f, S2 = 0.f;
#pragma unroll
            for (int w = 0; w < 4; ++w) {
                const float2 p = lnp[w][v][r];
                S1 += p.x; S2 += p.y;
            }
            const float mu  = S1 * (1.f / 128.f);
            const float var = S2 * (1.f / 128.f) - mu * mu;
            const float rs  = rsqrtf(var + LN_EPS);
            const int el = (v & 1) * 16 + r;
            const bool ok = (e0 + el) < E;
            const long orow = ((v < 2) ? 0L : (long)E) + e0 + el;
#pragma unroll
            for (int t = 0; t < 2; ++t) {
                const int fq = wave * 32 + t * 16 + q * 4;
                const float4 gv = *(const float4*)(&bgl[2][fq]);
                const float4 bv = *(const float4*)(&bgl[3][fq]);
                const f32x4 a = acc[t][v];
                float4 o;
                o.x = (a[0] - mu) * rs * gv.x + bv.x;
                o.y = (a[1] - mu) * rs * gv.y + bv.y;
                o.z = (a[2] - mu) * rs * gv.z + bv.z;
                o.w = (a[3] - mu) * rs * gv.w + bv.w;
                if (ok)
                    *(float4*)(out + orow * 128 + fq) = o;
            }
        }
    }
}

extern "C" void kernel_launch(void* const* d_in, const int* in_sizes, int n_in,
                              void* d_out, int out_size, void* d_ws, size_t ws_size,
                              hipStream_t stream) {
    // Validated interface: dict order, fp32 inputs, fp32 output.
    const float* inR   = (const float*)d_in[0];
    const float* inL   = (const float*)d_in[1];
    const float* W1    = (const float*)d_in[2];
    const float* b1    = (const float*)d_in[3];
    const float* W2    = (const float*)d_in[4];
    const float* b2    = (const float*)d_in[5];
    const float* gamma = (const float*)d_in[6];
    const float* beta  = (const float*)d_in[7];
    const int E = in_sizes[0] / 128;

    const int niters = (E + 31) / 32;
    const int d = (niters + 2047) / 2048;        // tiles per block (balanced)
    const int grid = (niters + d - 1) / d;
    mpnn_mfma<<<grid, 256, 0, stream>>>(inR, inL, W1, b1, W2, b2, gamma, beta,
                                        (float*)d_out, E, niters);
}